// Round 7
// baseline (411.902 us; speedup 1.0000x reference)
//
#include <hip/hip_runtime.h>
#include <hip/hip_bf16.h>
#include <math.h>

// Problem constants (reference: B=8, H=W=512)
#define Bsz    8
#define Wdim   512
#define HWv    (512 * 512)       // 262144 = 2^18
#define LOG2HW 18
#define NIMG   16                // {bg(0..7), fg(8..15)}
#define TILE   64                // 64x64 tiles -> 8x8 = 64 tiles per image
#define TPIX   (TILE * TILE)     // 4096

// ws layout (int32 units):
//   [0, NIMG*HWv)            labels: pixel -> tile root (local idx) or -1;
//                            tile-root slots -> final root after k_flatten
//   [NIMG*HWv, 2*NIMG*HWv)   areas: tile roots hold partial areas; final
//                            roots hold totals after k_flatten
//   [2*NIMG*HWv, +16)        per-image max area
//   then (8-byte aligned):   double sums[2]; int counts[2]

// ---------------- union-find (atomicMin only: parents monotone decreasing,
// links point to smaller index => lock-free correct). ----------------
__device__ __forceinline__ int uf_find(int* L, int x) {
  int p = L[x];
  while (p != x) {
    int gp = L[p];
    if (gp != p) atomicMin(&L[x], gp);  // grandparent compression (monotone)
    x = gp;
    p = L[x];
  }
  return x;
}

// Read-only find: no compression writes.
__device__ __forceinline__ int find_ro(const int* __restrict__ L, int x) {
  int p = L[x];
  while (p != x) { x = p; p = L[x]; }
  return x;
}

__device__ __forceinline__ void uf_union(int* L, int a, int b) {
  a = uf_find(L, a);
  b = uf_find(L, b);
  while (a != b) {
    if (a < b) { int t = a; a = b; b = t; }  // ensure a > b
    int old = atomicMin(&L[a], b);
    if (old == a) return;  // linked a -> b
    a = old;               // parent already lowered; keep merging
  }
}

// ---------------- kernels ----------------

// Per-tile CCL in LDS, run-based: a wave == one 64-px row. Pixels link
// directly to their run start (ballot, no atomics); vertical unions only at
// the leftmost pixel of each overlap segment.
__global__ void k_local(const float* __restrict__ cams, int* __restrict__ labels,
                        int* __restrict__ areas) {
  int img  = blockIdx.x >> 6;          // 0..15
  int tile = blockIdx.x & 63;          // 8x8 tiles
  int tY = tile >> 3, tX = tile & 7;
  int b = img & 7;
  bool fg = (img & 8) != 0;
  int gbase = img << LOG2HW;
  int oy = tY * TILE, ox = tX * TILE;
  int lane = threadIdx.x & 63;

  __shared__ int P[TPIX];              // parents, 16 KB
  __shared__ int A[TPIX];              // local areas, 16 KB

  // pass 1: mask load + per-row run-start init (wave covers exactly one row)
  #pragma unroll
  for (int it = 0; it < 16; ++it) {
    int i  = it * 256 + threadIdx.x;   // i & 63 == lane
    int ly = i >> 6;
    float c = cams[(b << LOG2HW) + ((oy + ly) << 9) + (ox + lane)];
    bool m = fg ? (c > 0.6f) : (c >= 0.2f);
    unsigned long long bm = __ballot(m);
    int par = -1;
    if (m) {
      unsigned long long below = (1ULL << lane) - 1ULL;
      unsigned long long z = (~bm) & below;       // zeros below this lane
      int rs = z ? (64 - __clzll(z)) : 0;          // run start = highest zero + 1
      par = (ly << 6) + rs;
    }
    P[i] = par;
    A[i] = 0;
  }
  __syncthreads();

  // pass 2: vertical unions, one per overlap segment (dedup via west pair)
  #pragma unroll
  for (int it = 0; it < 16; ++it) {
    int i = it * 256 + threadIdx.x;
    if (i >= TILE && P[i] >= 0 && P[i - TILE] >= 0) {
      bool skip = (lane > 0) && (P[i - 1] >= 0) && (P[i - TILE - 1] >= 0);
      if (!skip) uf_union(P, i, i - TILE);
    }
  }
  __syncthreads();

  // pass 3: compress to root + ballot-aggregated LDS area accumulation
  #pragma unroll
  for (int it = 0; it < 16; ++it) {
    int i = it * 256 + threadIdx.x;
    int r = -1;
    if (P[i] >= 0) { r = find_ro(P, i); P[i] = r; }
    bool valid = r >= 0;
    unsigned long long pending = __ballot(valid);
    while (pending) {
      int leader = __ffsll((unsigned long long)pending) - 1;
      int lr = __shfl(r, leader);
      bool match = valid && (r == lr);
      unsigned long long mm = __ballot(match);
      if (lane == leader) atomicAdd(&A[lr], (int)__popcll(mm));
      pending &= ~mm;
      if (match) valid = false;
    }
  }
  __syncthreads();

  // pass 4: write labels (global idx of tile root) + root partial areas
  #pragma unroll
  for (int it = 0; it < 16; ++it) {
    int i  = it * 256 + threadIdx.x;
    int ly = i >> 6;
    int g  = ((oy + ly) << 9) + (ox + lane);
    int p  = P[i];
    int lab = -1;
    if (p >= 0) lab = ((oy + (p >> 6)) << 9) + (ox + (p & 63));
    labels[gbase + g] = lab;
    areas[gbase + g]  = (p == i) ? A[i] : 0;
  }
}

// Merge across tile boundaries, one union per contiguous overlap segment.
// Also folds the tiny init (maxa/sums/counts) into block 0.
__global__ void k_border(int* __restrict__ labels, int* __restrict__ maxa,
                         double* __restrict__ sums, int* __restrict__ counts) {
  if (blockIdx.x == 0) {
    if (threadIdx.x < NIMG) maxa[threadIdx.x] = 0;
    if (threadIdx.x < 2) { sums[threadIdx.x] = 0.0; counts[threadIdx.x] = 0; }
  }
  const int per_img = 14 * Wdim;       // 7168
  int t = blockIdx.x * blockDim.x + threadIdx.x;
  if (t >= NIMG * per_img) return;
  int img = t / per_img;
  int r   = t - img * per_img;
  int k = r >> 9, j = r & (Wdim - 1);
  int* L = labels + (img << LOG2HW);
  // mask-ness (>=0 vs -1) of label slots is immutable here => dedup stable.
  if (k < 7) {                          // vertical border: x = 64k+63, union east
    int x = TILE * k + (TILE - 1);
    int p = (j << 9) + x, q = p + 1;    // j = y
    if (L[p] >= 0 && L[q] >= 0) {
      bool skip = (j > 0) && (L[p - Wdim] >= 0) && (L[q - Wdim] >= 0);
      if (!skip) uf_union(L, p, q);
    }
  } else {                              // horizontal border: y = 64(k-7)+63, union south
    int y = TILE * (k - 7) + (TILE - 1);
    int p = (y << 9) + j, q = p + Wdim; // j = x
    if (L[p] >= 0 && L[q] >= 0) {
      bool skip = (j > 0) && (L[p - 1] >= 0) && (L[q - 1] >= 0);
      if (!skip) uf_union(L, p, q);
    }
  }
}

// PUSH-ONLY flatten: only tile-root slots (area>0, ~4% of slots) do work:
// find final root, rewrite OWN label slot to it, push partial area with a
// NON-RETURNING atomic. Pixel labels are untouched (resolved via double hop
// in k_ce). Stale partials in non-final roots are never read and are always
// <= the component total, so k_max is unaffected.
// Races: pushes only target FINAL roots (area>0 originally, owners don't
// push to themselves); label rewrites store valid monotone ancestors.
__global__ void k_flatten(int* __restrict__ labels, int* __restrict__ areas) {
  int t = blockIdx.x * blockDim.x + threadIdx.x;
  int idx0 = t << 2;
  int4 ar = *(const int4*)&areas[idx0];
  if ((ar.x | ar.y | ar.z | ar.w) <= 0) return;   // all >= 0
  int img  = idx0 >> LOG2HW;
  int base = img << LOG2HW;
  int* L = labels + base;
  int self0 = idx0 - base;
  int4 lab = *(const int4*)&labels[idx0];
  if (ar.x > 0) { int r = find_ro(L, lab.x); L[self0]     = r; if (r != self0)     atomicAdd(&areas[base + r], ar.x); }
  if (ar.y > 0) { int r = find_ro(L, lab.y); L[self0 + 1] = r; if (r != self0 + 1) atomicAdd(&areas[base + r], ar.y); }
  if (ar.z > 0) { int r = find_ro(L, lab.z); L[self0 + 2] = r; if (r != self0 + 2) atomicAdd(&areas[base + r], ar.z); }
  if (ar.w > 0) { int r = find_ro(L, lab.w); L[self0 + 3] = r; if (r != self0 + 3) atomicAdd(&areas[base + r], ar.w); }
}

// Per-image max area: int4 streaming read, block-level max, 1 atomic/block.
__global__ void k_max(const int* __restrict__ areas, int* __restrict__ maxa) {
  int vidx = blockIdx.x * blockDim.x + threadIdx.x;   // int4 index
  const int4* a4 = (const int4*)areas;
  int4 v = a4[vidx];
  int m = max(max(v.x, v.y), max(v.z, v.w));
  #pragma unroll
  for (int off = 32; off > 0; off >>= 1)
    m = max(m, __shfl_down(m, off));
  __shared__ int lm[4];
  int wave = threadIdx.x >> 6;
  if ((threadIdx.x & 63) == 0) lm[wave] = m;
  __syncthreads();
  if (threadIdx.x == 0) {
    int bm = max(max(lm[0], lm[1]), max(lm[2], lm[3]));
    if (bm > 0) {
      int img = (vidx * 4) >> LOG2HW;
      atomicMax(&maxa[img], bm);
    }
  }
}

// Fused verdict + CE, guard-free: ALL stream loads (labels + 6x preds) issue
// before the dependent gather chain so preds HBM latency overlaps it.
// Chain per px: labels[px] (stream) -> labels[tileroot] (hot L2) ->
// areas[finalroot] (hot L2). Gathers are branch-free via clamped addresses.
__global__ void k_ce(const float* __restrict__ preds, const int* __restrict__ labels,
                     const int* __restrict__ areas, const int* __restrict__ maxa,
                     double* __restrict__ sums, int* __restrict__ counts) {
  int t = blockIdx.x * blockDim.x + threadIdx.x;      // 0..524287
  int idx0 = t << 2;
  int b  = idx0 >> LOG2HW;
  int p0 = idx0 & (HWv - 1);
  int maxb = maxa[b], maxf = maxa[8 + b];
  // stream loads, all independent:
  int4 lb = *(const int4*)&labels[idx0];
  int4 lf = *(const int4*)&labels[(8 << LOG2HW) + idx0];
  float4 A0[3], A1[3];
  #pragma unroll
  for (int i = 0; i < 3; i++) {
    const float* pb = preds + ((size_t)((i * Bsz + b) * 2) << LOG2HW);
    A0[i] = *(const float4*)&pb[p0];
    A1[i] = *(const float4*)&pb[HWv + p0];
  }
  const int* Lb = labels + (b << LOG2HW);
  const int* Lf = labels + ((8 + b) << LOG2HW);
  const int* ab = areas + (b << LOG2HW);
  const int* af = areas + ((8 + b) << LOG2HW);
  int lbj[4] = {lb.x, lb.y, lb.z, lb.w};
  int lfj[4] = {lf.x, lf.y, lf.z, lf.w};
  // gather round 1: tile root -> final root (branch-free, clamped addr)
  int rb[4], rf[4];
  #pragma unroll
  for (int j = 0; j < 4; j++) {
    rb[j] = Lb[max(lbj[j], 0)];
    rf[j] = Lf[max(lfj[j], 0)];
  }
  // gather round 2: final root -> total area
  bool vf[4], vb[4];
  #pragma unroll
  for (int j = 0; j < 4; j++) {
    int area_b = ab[max(rb[j], 0)];
    int area_f = af[max(rf[j], 0)];
    bool kb = (lbj[j] >= 0) && (2 * area_b > maxb);
    bool kf = (lfj[j] >= 0) && (2 * area_f > maxf);
    vb[j] = !kb;                       // bg valid where NOT kept
    vf[j] = kf;                        // fg valid where kept
  }
  int cf = (int)vf[0] + vf[1] + vf[2] + vf[3];
  int cb = (int)vb[0] + vb[1] + vb[2] + vb[3];
  float sfg = 0.f, sbg = 0.f;
  #pragma unroll
  for (int i = 0; i < 3; i++) {
    float d[4] = {A0[i].x - A1[i].x, A0[i].y - A1[i].y,
                  A0[i].z - A1[i].z, A0[i].w - A1[i].w};
    #pragma unroll
    for (int j = 0; j < 4; j++) {
      float sp = logf(1.f + expf(-fabsf(d[j])));
      sfg += vf[j] ? (fmaxf(d[j], 0.f) + sp) : 0.f;
      sbg += vb[j] ? (fmaxf(-d[j], 0.f) + sp) : 0.f;
    }
  }
  // block reduction: wave64 shuffle -> LDS -> 4 atomics/block
  #pragma unroll
  for (int off = 32; off > 0; off >>= 1) {
    sfg += __shfl_down(sfg, off);
    sbg += __shfl_down(sbg, off);
    cf  += __shfl_down(cf, off);
    cb  += __shfl_down(cb, off);
  }
  __shared__ float lsf[4], lsb[4];
  __shared__ int   lcf[4], lcb[4];
  int wave = threadIdx.x >> 6;
  if ((threadIdx.x & 63) == 0) {
    lsf[wave] = sfg; lsb[wave] = sbg; lcf[wave] = cf; lcb[wave] = cb;
  }
  __syncthreads();
  if (threadIdx.x == 0) {
    float tf = 0.f, tb = 0.f; int af_ = 0, ab_ = 0;
    #pragma unroll
    for (int w = 0; w < 4; w++) { tf += lsf[w]; tb += lsb[w]; af_ += lcf[w]; ab_ += lcb[w]; }
    atomicAdd(&sums[0], (double)tf);
    atomicAdd(&sums[1], (double)tb);
    atomicAdd(&counts[0], af_);
    atomicAdd(&counts[1], ab_);
  }
}

__global__ void k_final(const double* __restrict__ sums, const int* __restrict__ counts,
                        float* __restrict__ out) {
  if (threadIdx.x == 0 && blockIdx.x == 0) {
    double df = counts[0] > 0 ? (double)counts[0] : 1.0;
    double db = counts[1] > 0 ? (double)counts[1] : 1.0;
    out[0] = (float)(sums[0] / df + sums[1] / db);
  }
}

extern "C" void kernel_launch(void* const* d_in, const int* in_sizes, int n_in,
                              void* d_out, int out_size, void* d_ws, size_t ws_size,
                              hipStream_t stream) {
  (void)in_sizes; (void)n_in; (void)out_size; (void)ws_size;
  const float* preds = (const float*)d_in[0];  // [3,8,2,512,512] f32
  const float* cams  = (const float*)d_in[1];  // [8,1,512,512]  f32
  float* out = (float*)d_out;                  // scalar f32

  int* labels = (int*)d_ws;
  int* areas  = labels + NIMG * HWv;
  int* maxa   = areas + NIMG * HWv;
  double* sums = (double*)(maxa + 16);
  int* counts  = (int*)(sums + 2);

  const int threads = 256;

  k_local  <<<NIMG * 64, threads, 0, stream>>>(cams, labels, areas);
  k_border <<<(NIMG * 14 * Wdim + threads - 1) / threads, threads, 0, stream>>>(labels, maxa, sums, counts);
  k_flatten<<<NIMG * HWv / (threads * 4), threads, 0, stream>>>(labels, areas);
  k_max    <<<NIMG * HWv / (threads * 4), threads, 0, stream>>>(areas, maxa);
  k_ce     <<<Bsz * HWv / (threads * 4), threads, 0, stream>>>(preds, labels, areas, maxa, sums, counts);
  k_final  <<<1, 64, 0, stream>>>(sums, counts, out);
}

// Round 8
// 237.824 us; speedup vs baseline: 1.7320x; 1.7320x over previous
//
#include <hip/hip_runtime.h>
#include <hip/hip_bf16.h>
#include <math.h>

// Problem constants (reference: B=8, H=W=512)
#define Bsz    8
#define Wdim   512
#define HWv    (512 * 512)       // 262144 = 2^18
#define LOG2HW 18
#define NIMG   16                // {bg(0..7), fg(8..15)}
#define TILE   64                // 64x64 tiles -> 8x8 = 64 tiles per image
#define TPIX   (TILE * TILE)     // 4096

// ws layout (int32 units):
//   [0, NIMG*HWv)            labels: pixel -> tile root (in-tile) or -1;
//                            tile-root slots -> final root after k_flatten
//   [NIMG*HWv, 2*NIMG*HWv)   areas: tile roots hold partials; final roots
//                            hold totals after k_flatten; 0 elsewhere
//   [2*NIMG*HWv, +16)        per-image max area
//   then (8-byte aligned):   double sums[2]; int counts[2]

// ---------------- union-find (atomicMin only: parents monotone decreasing,
// links point to smaller index => lock-free correct). ----------------
__device__ __forceinline__ int uf_find(int* L, int x) {
  int p = L[x];
  while (p != x) {
    int gp = L[p];
    if (gp != p) atomicMin(&L[x], gp);  // grandparent compression (monotone)
    x = gp;
    p = L[x];
  }
  return x;
}

// Read-only find: no compression writes.
__device__ __forceinline__ int find_ro(const int* __restrict__ L, int x) {
  int p = L[x];
  while (p != x) { x = p; p = L[x]; }
  return x;
}

__device__ __forceinline__ void uf_union(int* L, int a, int b) {
  a = uf_find(L, a);
  b = uf_find(L, b);
  while (a != b) {
    if (a < b) { int t = a; a = b; b = t; }  // ensure a > b
    int old = atomicMin(&L[a], b);
    if (old == a) return;  // linked a -> b
    a = old;               // parent already lowered; keep merging
  }
}

// ---------------- kernels ----------------

// Per-tile CCL in LDS, run-based: a wave == one 64-px row. Pixels link
// directly to their run start (ballot, no atomics); vertical unions only at
// the leftmost pixel of each overlap segment.
__global__ void k_local(const float* __restrict__ cams, int* __restrict__ labels,
                        int* __restrict__ areas) {
  int img  = blockIdx.x >> 6;          // 0..15
  int tile = blockIdx.x & 63;          // 8x8 tiles
  int tY = tile >> 3, tX = tile & 7;
  int b = img & 7;
  bool fg = (img & 8) != 0;
  int gbase = img << LOG2HW;
  int oy = tY * TILE, ox = tX * TILE;
  int lane = threadIdx.x & 63;

  __shared__ int P[TPIX];              // parents, 16 KB
  __shared__ int A[TPIX];              // local areas, 16 KB

  // pass 1: mask load + per-row run-start init (wave covers exactly one row)
  #pragma unroll
  for (int it = 0; it < 16; ++it) {
    int i  = it * 256 + threadIdx.x;   // i & 63 == lane
    int ly = i >> 6;
    float c = cams[(b << LOG2HW) + ((oy + ly) << 9) + (ox + lane)];
    bool m = fg ? (c > 0.6f) : (c >= 0.2f);
    unsigned long long bm = __ballot(m);
    int par = -1;
    if (m) {
      unsigned long long below = (1ULL << lane) - 1ULL;
      unsigned long long z = (~bm) & below;       // zeros below this lane
      int rs = z ? (64 - __clzll(z)) : 0;          // run start = highest zero + 1
      par = (ly << 6) + rs;
    }
    P[i] = par;
    A[i] = 0;
  }
  __syncthreads();

  // pass 2: vertical unions, one per overlap segment (dedup via west pair)
  #pragma unroll
  for (int it = 0; it < 16; ++it) {
    int i = it * 256 + threadIdx.x;
    if (i >= TILE && P[i] >= 0 && P[i - TILE] >= 0) {
      bool skip = (lane > 0) && (P[i - 1] >= 0) && (P[i - TILE - 1] >= 0);
      if (!skip) uf_union(P, i, i - TILE);
    }
  }
  __syncthreads();

  // pass 3: compress to root + ballot-aggregated LDS area accumulation
  #pragma unroll
  for (int it = 0; it < 16; ++it) {
    int i = it * 256 + threadIdx.x;
    int r = -1;
    if (P[i] >= 0) { r = find_ro(P, i); P[i] = r; }
    bool valid = r >= 0;
    unsigned long long pending = __ballot(valid);
    while (pending) {
      int leader = __ffsll((unsigned long long)pending) - 1;
      int lr = __shfl(r, leader);
      bool match = valid && (r == lr);
      unsigned long long mm = __ballot(match);
      if (lane == leader) atomicAdd(&A[lr], (int)__popcll(mm));
      pending &= ~mm;
      if (match) valid = false;
    }
  }
  __syncthreads();

  // pass 4: write labels (global idx of tile root) + root partial areas
  #pragma unroll
  for (int it = 0; it < 16; ++it) {
    int i  = it * 256 + threadIdx.x;
    int ly = i >> 6;
    int g  = ((oy + ly) << 9) + (ox + lane);
    int p  = P[i];
    int lab = -1;
    if (p >= 0) lab = ((oy + (p >> 6)) << 9) + (ox + (p & 63));
    labels[gbase + g] = lab;
    areas[gbase + g]  = (p == i) ? A[i] : 0;
  }
}

// Merge across tile boundaries, one union per contiguous overlap segment.
// Also folds the tiny init (maxa/sums/counts) into block 0.
__global__ void k_border(int* __restrict__ labels, int* __restrict__ maxa,
                         double* __restrict__ sums, int* __restrict__ counts) {
  if (blockIdx.x == 0) {
    if (threadIdx.x < NIMG) maxa[threadIdx.x] = 0;
    if (threadIdx.x < 2) { sums[threadIdx.x] = 0.0; counts[threadIdx.x] = 0; }
  }
  const int per_img = 14 * Wdim;       // 7168
  int t = blockIdx.x * blockDim.x + threadIdx.x;
  if (t >= NIMG * per_img) return;
  int img = t / per_img;
  int r   = t - img * per_img;
  int k = r >> 9, j = r & (Wdim - 1);
  int* L = labels + (img << LOG2HW);
  // mask-ness (>=0 vs -1) of label slots is immutable here => dedup stable.
  if (k < 7) {                          // vertical border: x = 64k+63, union east
    int x = TILE * k + (TILE - 1);
    int p = (j << 9) + x, q = p + 1;    // j = y
    if (L[p] >= 0 && L[q] >= 0) {
      bool skip = (j > 0) && (L[p - Wdim] >= 0) && (L[q - Wdim] >= 0);
      if (!skip) uf_union(L, p, q);
    }
  } else {                              // horizontal border: y = 64(k-7)+63, union south
    int y = TILE * (k - 7) + (TILE - 1);
    int p = (y << 9) + j, q = p + Wdim; // j = x
    if (L[p] >= 0 && L[q] >= 0) {
      bool skip = (j > 0) && (L[p - 1] >= 0) && (L[q - 1] >= 0);
      if (!skip) uf_union(L, p, q);
    }
  }
}

// PUSH-ONLY flatten: only tile-root slots (area>0, ~4% of slots) do work:
// find final root, rewrite OWN label slot to it, push partial area with a
// NON-RETURNING atomic. Pixel labels untouched. Stale partials at non-final
// roots are <= component totals, so k_max is unaffected.
__global__ void k_flatten(int* __restrict__ labels, int* __restrict__ areas) {
  int t = blockIdx.x * blockDim.x + threadIdx.x;
  int idx0 = t << 2;
  int4 ar = *(const int4*)&areas[idx0];
  if ((ar.x | ar.y | ar.z | ar.w) <= 0) return;   // all >= 0
  int img  = idx0 >> LOG2HW;
  int base = img << LOG2HW;
  int* L = labels + base;
  int self0 = idx0 - base;
  int4 lab = *(const int4*)&labels[idx0];
  if (ar.x > 0) { int r = find_ro(L, lab.x); L[self0]     = r; if (r != self0)     atomicAdd(&areas[base + r], ar.x); }
  if (ar.y > 0) { int r = find_ro(L, lab.y); L[self0 + 1] = r; if (r != self0 + 1) atomicAdd(&areas[base + r], ar.y); }
  if (ar.z > 0) { int r = find_ro(L, lab.z); L[self0 + 2] = r; if (r != self0 + 2) atomicAdd(&areas[base + r], ar.z); }
  if (ar.w > 0) { int r = find_ro(L, lab.w); L[self0 + 3] = r; if (r != self0 + 3) atomicAdd(&areas[base + r], ar.w); }
}

// Per-image max area: int4 streaming read, block-level max, 1 atomic/block.
__global__ void k_max(const int* __restrict__ areas, int* __restrict__ maxa) {
  int vidx = blockIdx.x * blockDim.x + threadIdx.x;   // int4 index
  const int4* a4 = (const int4*)areas;
  int4 v = a4[vidx];
  int m = max(max(v.x, v.y), max(v.z, v.w));
  #pragma unroll
  for (int off = 32; off > 0; off >>= 1)
    m = max(m, __shfl_down(m, off));
  __shared__ int lm[4];
  int wave = threadIdx.x >> 6;
  if ((threadIdx.x & 63) == 0) lm[wave] = m;
  __syncthreads();
  if (threadIdx.x == 0) {
    int bm = max(max(lm[0], lm[1]), max(lm[2], lm[3]));
    if (bm > 0) {
      int img = (vidx * 4) >> LOG2HW;
      atomicMax(&maxa[img], bm);
    }
  }
}

// Fused verdict + CE, one block per (batch, tile). Exploits the invariant
// that every pixel's label points to a tile root INSIDE its own tile:
// verdicts are built once per ROOT (one global gather each, ~150K total
// device-wide) into an LDS table; per-pixel resolution is an LDS read.
__global__ void k_keepce(const float* __restrict__ preds,
                         const int* __restrict__ labels,
                         const int* __restrict__ areas,
                         const int* __restrict__ maxa,
                         double* __restrict__ sums, int* __restrict__ counts) {
  int b    = blockIdx.x >> 6;          // 0..7
  int tile = blockIdx.x & 63;
  int tY = tile >> 3, tX = tile & 7;
  int oy = tY * TILE, ox = tX * TILE;
  int basebg = b << LOG2HW, basefg = (8 + b) << LOG2HW;
  int maxb = maxa[b], maxf = maxa[8 + b];

  __shared__ int Vbg[TPIX];            // 16 KB verdict tables (root slots only)
  __shared__ int Vfg[TPIX];            // 16 KB

  int4 lb4[4], lf4[4];
  // phase 1: stream labels+areas; root slots (area>0) resolve their verdict
  // with ONE gather (their label already holds the final root). Root pixels'
  // register labels are redirected to self (their global label points
  // cross-tile after flatten, but their own V entry is the right verdict).
  #pragma unroll
  for (int it = 0; it < 4; ++it) {
    int i  = (it * 256 + threadIdx.x) << 2;   // in-tile index of 4-px group
    int ly = i >> 6, lx = i & 63;
    int g  = ((oy + ly) << 9) + (ox + lx);    // in-image index
    int4 lb = *(const int4*)&labels[basebg + g];
    int4 lf = *(const int4*)&labels[basefg + g];
    int4 ab = *(const int4*)&areas[basebg + g];
    int4 af = *(const int4*)&areas[basefg + g];
    if (ab.x > 0) { Vbg[i+0] = (2 * areas[basebg + lb.x] > maxb); lb.x = g + 0; }
    if (ab.y > 0) { Vbg[i+1] = (2 * areas[basebg + lb.y] > maxb); lb.y = g + 1; }
    if (ab.z > 0) { Vbg[i+2] = (2 * areas[basebg + lb.z] > maxb); lb.z = g + 2; }
    if (ab.w > 0) { Vbg[i+3] = (2 * areas[basebg + lb.w] > maxb); lb.w = g + 3; }
    if (af.x > 0) { Vfg[i+0] = (2 * areas[basefg + lf.x] > maxf); lf.x = g + 0; }
    if (af.y > 0) { Vfg[i+1] = (2 * areas[basefg + lf.y] > maxf); lf.y = g + 1; }
    if (af.z > 0) { Vfg[i+2] = (2 * areas[basefg + lf.z] > maxf); lf.z = g + 2; }
    if (af.w > 0) { Vfg[i+3] = (2 * areas[basefg + lf.w] > maxf); lf.w = g + 3; }
    lb4[it] = lb; lf4[it] = lf;
  }
  __syncthreads();

  // phase 2: CE with LDS verdict lookups (in-tile: loc = (gy&63)*64+(gx&63))
  float sfg = 0.f, sbg = 0.f;
  int cf = 0, cb = 0;
  #pragma unroll
  for (int it = 0; it < 4; ++it) {
    int i  = (it * 256 + threadIdx.x) << 2;
    int ly = i >> 6, lx = i & 63;
    int g  = ((oy + ly) << 9) + (ox + lx);
    float4 A0[3], A1[3];
    #pragma unroll
    for (int p = 0; p < 3; p++) {
      const float* pb = preds + ((size_t)((p * Bsz + b) * 2) << LOG2HW);
      A0[p] = *(const float4*)&pb[g];
      A1[p] = *(const float4*)&pb[HWv + g];
    }
    int lbj[4] = {lb4[it].x, lb4[it].y, lb4[it].z, lb4[it].w};
    int lfj[4] = {lf4[it].x, lf4[it].y, lf4[it].z, lf4[it].w};
    bool vf[4], vb[4];
    #pragma unroll
    for (int j = 0; j < 4; j++) {
      int locb = (((lbj[j] >> 9) & 63) << 6) | (lbj[j] & 63);
      int locf = (((lfj[j] >> 9) & 63) << 6) | (lfj[j] & 63);
      bool kb = (lbj[j] >= 0) && (Vbg[locb] != 0);
      bool kf = (lfj[j] >= 0) && (Vfg[locf] != 0);
      vb[j] = !kb;                     // bg valid where NOT kept
      vf[j] = kf;                      // fg valid where kept
    }
    cf += (int)vf[0] + vf[1] + vf[2] + vf[3];
    cb += (int)vb[0] + vb[1] + vb[2] + vb[3];
    #pragma unroll
    for (int p = 0; p < 3; p++) {
      float d[4] = {A0[p].x - A1[p].x, A0[p].y - A1[p].y,
                    A0[p].z - A1[p].z, A0[p].w - A1[p].w};
      #pragma unroll
      for (int j = 0; j < 4; j++) {
        float sp = logf(1.f + expf(-fabsf(d[j])));
        sfg += vf[j] ? (fmaxf(d[j], 0.f) + sp) : 0.f;
        sbg += vb[j] ? (fmaxf(-d[j], 0.f) + sp) : 0.f;
      }
    }
  }
  // block reduction: wave64 shuffle -> LDS -> 4 atomics/block
  #pragma unroll
  for (int off = 32; off > 0; off >>= 1) {
    sfg += __shfl_down(sfg, off);
    sbg += __shfl_down(sbg, off);
    cf  += __shfl_down(cf, off);
    cb  += __shfl_down(cb, off);
  }
  __shared__ float lsf[4], lsb[4];
  __shared__ int   lcf[4], lcb[4];
  int wave = threadIdx.x >> 6;
  if ((threadIdx.x & 63) == 0) {
    lsf[wave] = sfg; lsb[wave] = sbg; lcf[wave] = cf; lcb[wave] = cb;
  }
  __syncthreads();
  if (threadIdx.x == 0) {
    float tf = 0.f, tb = 0.f; int af_ = 0, ab_ = 0;
    #pragma unroll
    for (int w = 0; w < 4; w++) { tf += lsf[w]; tb += lsb[w]; af_ += lcf[w]; ab_ += lcb[w]; }
    atomicAdd(&sums[0], (double)tf);
    atomicAdd(&sums[1], (double)tb);
    atomicAdd(&counts[0], af_);
    atomicAdd(&counts[1], ab_);
  }
}

__global__ void k_final(const double* __restrict__ sums, const int* __restrict__ counts,
                        float* __restrict__ out) {
  if (threadIdx.x == 0 && blockIdx.x == 0) {
    double df = counts[0] > 0 ? (double)counts[0] : 1.0;
    double db = counts[1] > 0 ? (double)counts[1] : 1.0;
    out[0] = (float)(sums[0] / df + sums[1] / db);
  }
}

extern "C" void kernel_launch(void* const* d_in, const int* in_sizes, int n_in,
                              void* d_out, int out_size, void* d_ws, size_t ws_size,
                              hipStream_t stream) {
  (void)in_sizes; (void)n_in; (void)out_size; (void)ws_size;
  const float* preds = (const float*)d_in[0];  // [3,8,2,512,512] f32
  const float* cams  = (const float*)d_in[1];  // [8,1,512,512]  f32
  float* out = (float*)d_out;                  // scalar f32

  int* labels = (int*)d_ws;
  int* areas  = labels + NIMG * HWv;
  int* maxa   = areas + NIMG * HWv;
  double* sums = (double*)(maxa + 16);
  int* counts  = (int*)(sums + 2);

  const int threads = 256;

  k_local  <<<NIMG * 64, threads, 0, stream>>>(cams, labels, areas);
  k_border <<<(NIMG * 14 * Wdim + threads - 1) / threads, threads, 0, stream>>>(labels, maxa, sums, counts);
  k_flatten<<<NIMG * HWv / (threads * 4), threads, 0, stream>>>(labels, areas);
  k_max    <<<NIMG * HWv / (threads * 4), threads, 0, stream>>>(areas, maxa);
  k_keepce <<<Bsz * 64, threads, 0, stream>>>(preds, labels, areas, maxa, sums, counts);
  k_final  <<<1, 64, 0, stream>>>(sums, counts, out);
}

// Round 9
// 215.201 us; speedup vs baseline: 1.9140x; 1.1051x over previous
//
#include <hip/hip_runtime.h>
#include <hip/hip_bf16.h>
#include <math.h>

// Problem constants (reference: B=8, H=W=512)
#define Bsz    8
#define Wdim   512
#define HWv    (512 * 512)       // 262144 = 2^18
#define LOG2HW 18
#define NIMG   16                // {bg(0..7), fg(8..15)}
#define TILE   64                // 64x64 tiles -> 8x8 = 64 tiles per image
#define TPIX   (TILE * TILE)     // 4096

// ws layout (int32 units):
//   [0, NIMG*HWv)            labels: pixel -> tile root (in-tile) or -1;
//                            tile-root slots -> final root after k_flatten
//   [NIMG*HWv, 2*NIMG*HWv)   areas: tile roots hold partials; final roots
//                            hold totals after k_flatten; 0 elsewhere
//   [2*NIMG*HWv, +16)        per-image max area
//   then (8-byte aligned):   double sums[2]; int counts[2]

// ---------------- union-find (atomicMin only: parents monotone decreasing,
// links point to smaller index => lock-free correct). ----------------
__device__ __forceinline__ int uf_find(int* L, int x) {
  int p = L[x];
  while (p != x) {
    int gp = L[p];
    if (gp != p) atomicMin(&L[x], gp);  // grandparent compression (monotone)
    x = gp;
    p = L[x];
  }
  return x;
}

// Read-only find: no compression writes.
__device__ __forceinline__ int find_ro(const int* __restrict__ L, int x) {
  int p = L[x];
  while (p != x) { x = p; p = L[x]; }
  return x;
}

__device__ __forceinline__ void uf_union(int* L, int a, int b) {
  a = uf_find(L, a);
  b = uf_find(L, b);
  while (a != b) {
    if (a < b) { int t = a; a = b; b = t; }  // ensure a > b
    int old = atomicMin(&L[a], b);
    if (old == a) return;  // linked a -> b
    a = old;               // parent already lowered; keep merging
  }
}

// ---------------- kernels ----------------

// Per-tile CCL in LDS, run-based: a wave == one 64-px row. Pixels link
// directly to their run start (ballot, no atomics); vertical unions only at
// the leftmost pixel of each overlap segment. Finds are PER-RUN (run-start
// lanes only); other lanes take the root via shuffle.
__global__ void k_local(const float* __restrict__ cams, int* __restrict__ labels,
                        int* __restrict__ areas) {
  int img  = blockIdx.x >> 6;          // 0..15
  int tile = blockIdx.x & 63;          // 8x8 tiles
  int tY = tile >> 3, tX = tile & 7;
  int b = img & 7;
  bool fg = (img & 8) != 0;
  int gbase = img << LOG2HW;
  int oy = tY * TILE, ox = tX * TILE;
  int lane = threadIdx.x & 63;

  __shared__ int P[TPIX];              // parents, 16 KB
  __shared__ int A[TPIX];              // local areas, 16 KB

  // pass 1: mask load + per-row run-start init (wave covers exactly one row)
  #pragma unroll
  for (int it = 0; it < 16; ++it) {
    int i  = it * 256 + threadIdx.x;   // i & 63 == lane
    int ly = i >> 6;
    float c = cams[(b << LOG2HW) + ((oy + ly) << 9) + (ox + lane)];
    bool m = fg ? (c > 0.6f) : (c >= 0.2f);
    unsigned long long bm = __ballot(m);
    int par = -1;
    if (m) {
      unsigned long long below = (1ULL << lane) - 1ULL;
      unsigned long long z = (~bm) & below;       // zeros below this lane
      int rs = z ? (64 - __clzll(z)) : 0;          // run start = highest zero + 1
      par = (ly << 6) + rs;
    }
    P[i] = par;
    A[i] = 0;
  }
  __syncthreads();

  // pass 2: vertical unions, one per overlap segment (dedup via west pair)
  #pragma unroll
  for (int it = 0; it < 16; ++it) {
    int i = it * 256 + threadIdx.x;
    if (i >= TILE && P[i] >= 0 && P[i - TILE] >= 0) {
      bool skip = (lane > 0) && (P[i - 1] >= 0) && (P[i - TILE - 1] >= 0);
      if (!skip) uf_union(P, i, i - TILE);
    }
  }
  __syncthreads();

  // pass 3: PER-RUN find + shuffle broadcast + per-run area add.
  // Run-start lanes (~11-16 of 64) chase the tree; everyone else gets the
  // root via shuffle from their run start (same wave = same row). Plain
  // store P[i]=root gives maximal compression; stores are final roots so
  // concurrent find_ro by other waves stays correct (monotone ancestors).
  #pragma unroll
  for (int it = 0; it < 16; ++it) {
    int i = it * 256 + threadIdx.x;
    bool m = P[i] >= 0;
    unsigned long long bm = __ballot(m);
    int rs = 0;
    if (m) {
      unsigned long long below = (1ULL << lane) - 1ULL;
      unsigned long long z = (~bm) & below;
      rs = z ? (64 - __clzll(z)) : 0;
    }
    bool isStart = m && (rs == lane);
    int r = -1;
    if (isStart) r = find_ro(P, i);
    int root = __shfl(r, rs);          // valid wherever m
    if (m) P[i] = root;
    if (isStart) {
      unsigned long long t = (~bm) >> lane;
      int runlen = t ? (__ffsll((long long)t) - 1) : (64 - lane);
      atomicAdd(&A[root], runlen);
    }
  }
  __syncthreads();

  // pass 4: pure-read write-out: labels (global idx of tile root, already
  // fully compressed) + root partial areas
  #pragma unroll
  for (int it = 0; it < 16; ++it) {
    int i  = it * 256 + threadIdx.x;
    int ly = i >> 6;
    int g  = ((oy + ly) << 9) + (ox + lane);
    int p  = P[i];
    int lab = -1;
    if (p >= 0) lab = ((oy + (p >> 6)) << 9) + (ox + (p & 63));
    labels[gbase + g] = lab;
    areas[gbase + g]  = (p == i) ? A[i] : 0;
  }
}

// Merge across tile boundaries, one union per contiguous overlap segment.
// Also folds the tiny init (maxa/sums/counts) into block 0.
__global__ void k_border(int* __restrict__ labels, int* __restrict__ maxa,
                         double* __restrict__ sums, int* __restrict__ counts) {
  if (blockIdx.x == 0) {
    if (threadIdx.x < NIMG) maxa[threadIdx.x] = 0;
    if (threadIdx.x < 2) { sums[threadIdx.x] = 0.0; counts[threadIdx.x] = 0; }
  }
  const int per_img = 14 * Wdim;       // 7168
  int t = blockIdx.x * blockDim.x + threadIdx.x;
  if (t >= NIMG * per_img) return;
  int img = t / per_img;
  int r   = t - img * per_img;
  int k = r >> 9, j = r & (Wdim - 1);
  int* L = labels + (img << LOG2HW);
  // mask-ness (>=0 vs -1) of label slots is immutable here => dedup stable.
  if (k < 7) {                          // vertical border: x = 64k+63, union east
    int x = TILE * k + (TILE - 1);
    int p = (j << 9) + x, q = p + 1;    // j = y
    if (L[p] >= 0 && L[q] >= 0) {
      bool skip = (j > 0) && (L[p - Wdim] >= 0) && (L[q - Wdim] >= 0);
      if (!skip) uf_union(L, p, q);
    }
  } else {                              // horizontal border: y = 64(k-7)+63, union south
    int y = TILE * (k - 7) + (TILE - 1);
    int p = (y << 9) + j, q = p + Wdim; // j = x
    if (L[p] >= 0 && L[q] >= 0) {
      bool skip = (j > 0) && (L[p - 1] >= 0) && (L[q - 1] >= 0);
      if (!skip) uf_union(L, p, q);
    }
  }
}

// PUSH-ONLY flatten: only tile-root slots (area>0, ~4% of slots) do work:
// find final root, rewrite OWN label slot to it, push partial area with a
// NON-RETURNING atomic. Pixel labels untouched. Stale partials at non-final
// roots are <= component totals, so k_max is unaffected.
__global__ void k_flatten(int* __restrict__ labels, int* __restrict__ areas) {
  int t = blockIdx.x * blockDim.x + threadIdx.x;
  int idx0 = t << 2;
  int4 ar = *(const int4*)&areas[idx0];
  if ((ar.x | ar.y | ar.z | ar.w) <= 0) return;   // all >= 0
  int img  = idx0 >> LOG2HW;
  int base = img << LOG2HW;
  int* L = labels + base;
  int self0 = idx0 - base;
  int4 lab = *(const int4*)&labels[idx0];
  if (ar.x > 0) { int r = find_ro(L, lab.x); L[self0]     = r; if (r != self0)     atomicAdd(&areas[base + r], ar.x); }
  if (ar.y > 0) { int r = find_ro(L, lab.y); L[self0 + 1] = r; if (r != self0 + 1) atomicAdd(&areas[base + r], ar.y); }
  if (ar.z > 0) { int r = find_ro(L, lab.z); L[self0 + 2] = r; if (r != self0 + 2) atomicAdd(&areas[base + r], ar.z); }
  if (ar.w > 0) { int r = find_ro(L, lab.w); L[self0 + 3] = r; if (r != self0 + 3) atomicAdd(&areas[base + r], ar.w); }
}

// Per-image max area: int4 streaming read, block-level max, 1 atomic/block.
__global__ void k_max(const int* __restrict__ areas, int* __restrict__ maxa) {
  int vidx = blockIdx.x * blockDim.x + threadIdx.x;   // int4 index
  const int4* a4 = (const int4*)areas;
  int4 v = a4[vidx];
  int m = max(max(v.x, v.y), max(v.z, v.w));
  #pragma unroll
  for (int off = 32; off > 0; off >>= 1)
    m = max(m, __shfl_down(m, off));
  __shared__ int lm[4];
  int wave = threadIdx.x >> 6;
  if ((threadIdx.x & 63) == 0) lm[wave] = m;
  __syncthreads();
  if (threadIdx.x == 0) {
    int bm = max(max(lm[0], lm[1]), max(lm[2], lm[3]));
    if (bm > 0) {
      int img = (vidx * 4) >> LOG2HW;
      atomicMax(&maxa[img], bm);
    }
  }
}

// Fused verdict + CE, one block per (batch, tile). Exploits the invariant
// that every pixel's label points to a tile root INSIDE its own tile:
// verdicts are built once per ROOT (one global gather each, ~150K total
// device-wide) into an LDS table; per-pixel resolution is an LDS read.
__global__ void k_keepce(const float* __restrict__ preds,
                         const int* __restrict__ labels,
                         const int* __restrict__ areas,
                         const int* __restrict__ maxa,
                         double* __restrict__ sums, int* __restrict__ counts) {
  int b    = blockIdx.x >> 6;          // 0..7
  int tile = blockIdx.x & 63;
  int tY = tile >> 3, tX = tile & 7;
  int oy = tY * TILE, ox = tX * TILE;
  int basebg = b << LOG2HW, basefg = (8 + b) << LOG2HW;
  int maxb = maxa[b], maxf = maxa[8 + b];

  __shared__ int Vbg[TPIX];            // 16 KB verdict tables (root slots only)
  __shared__ int Vfg[TPIX];            // 16 KB

  int4 lb4[4], lf4[4];
  // phase 1: stream labels+areas; root slots (area>0) resolve their verdict
  // with ONE gather (their label already holds the final root). Root pixels'
  // register labels are redirected to self.
  #pragma unroll
  for (int it = 0; it < 4; ++it) {
    int i  = (it * 256 + threadIdx.x) << 2;   // in-tile index of 4-px group
    int ly = i >> 6, lx = i & 63;
    int g  = ((oy + ly) << 9) + (ox + lx);    // in-image index
    int4 lb = *(const int4*)&labels[basebg + g];
    int4 lf = *(const int4*)&labels[basefg + g];
    int4 ab = *(const int4*)&areas[basebg + g];
    int4 af = *(const int4*)&areas[basefg + g];
    if (ab.x > 0) { Vbg[i+0] = (2 * areas[basebg + lb.x] > maxb); lb.x = g + 0; }
    if (ab.y > 0) { Vbg[i+1] = (2 * areas[basebg + lb.y] > maxb); lb.y = g + 1; }
    if (ab.z > 0) { Vbg[i+2] = (2 * areas[basebg + lb.z] > maxb); lb.z = g + 2; }
    if (ab.w > 0) { Vbg[i+3] = (2 * areas[basebg + lb.w] > maxb); lb.w = g + 3; }
    if (af.x > 0) { Vfg[i+0] = (2 * areas[basefg + lf.x] > maxf); lf.x = g + 0; }
    if (af.y > 0) { Vfg[i+1] = (2 * areas[basefg + lf.y] > maxf); lf.y = g + 1; }
    if (af.z > 0) { Vfg[i+2] = (2 * areas[basefg + lf.z] > maxf); lf.z = g + 2; }
    if (af.w > 0) { Vfg[i+3] = (2 * areas[basefg + lf.w] > maxf); lf.w = g + 3; }
    lb4[it] = lb; lf4[it] = lf;
  }
  __syncthreads();

  // phase 2: CE with LDS verdict lookups (in-tile: loc = (gy&63)*64+(gx&63))
  float sfg = 0.f, sbg = 0.f;
  int cf = 0, cb = 0;
  #pragma unroll
  for (int it = 0; it < 4; ++it) {
    int i  = (it * 256 + threadIdx.x) << 2;
    int ly = i >> 6, lx = i & 63;
    int g  = ((oy + ly) << 9) + (ox + lx);
    float4 A0[3], A1[3];
    #pragma unroll
    for (int p = 0; p < 3; p++) {
      const float* pb = preds + ((size_t)((p * Bsz + b) * 2) << LOG2HW);
      A0[p] = *(const float4*)&pb[g];
      A1[p] = *(const float4*)&pb[HWv + g];
    }
    int lbj[4] = {lb4[it].x, lb4[it].y, lb4[it].z, lb4[it].w};
    int lfj[4] = {lf4[it].x, lf4[it].y, lf4[it].z, lf4[it].w};
    bool vf[4], vb[4];
    #pragma unroll
    for (int j = 0; j < 4; j++) {
      int locb = (((lbj[j] >> 9) & 63) << 6) | (lbj[j] & 63);
      int locf = (((lfj[j] >> 9) & 63) << 6) | (lfj[j] & 63);
      bool kb = (lbj[j] >= 0) && (Vbg[locb] != 0);
      bool kf = (lfj[j] >= 0) && (Vfg[locf] != 0);
      vb[j] = !kb;                     // bg valid where NOT kept
      vf[j] = kf;                      // fg valid where kept
    }
    cf += (int)vf[0] + vf[1] + vf[2] + vf[3];
    cb += (int)vb[0] + vb[1] + vb[2] + vb[3];
    #pragma unroll
    for (int p = 0; p < 3; p++) {
      float d[4] = {A0[p].x - A1[p].x, A0[p].y - A1[p].y,
                    A0[p].z - A1[p].z, A0[p].w - A1[p].w};
      #pragma unroll
      for (int j = 0; j < 4; j++) {
        float sp = logf(1.f + expf(-fabsf(d[j])));
        sfg += vf[j] ? (fmaxf(d[j], 0.f) + sp) : 0.f;
        sbg += vb[j] ? (fmaxf(-d[j], 0.f) + sp) : 0.f;
      }
    }
  }
  // block reduction: wave64 shuffle -> LDS -> 4 atomics/block
  #pragma unroll
  for (int off = 32; off > 0; off >>= 1) {
    sfg += __shfl_down(sfg, off);
    sbg += __shfl_down(sbg, off);
    cf  += __shfl_down(cf, off);
    cb  += __shfl_down(cb, off);
  }
  __shared__ float lsf[4], lsb[4];
  __shared__ int   lcf[4], lcb[4];
  int wave = threadIdx.x >> 6;
  if ((threadIdx.x & 63) == 0) {
    lsf[wave] = sfg; lsb[wave] = sbg; lcf[wave] = cf; lcb[wave] = cb;
  }
  __syncthreads();
  if (threadIdx.x == 0) {
    float tf = 0.f, tb = 0.f; int af_ = 0, ab_ = 0;
    #pragma unroll
    for (int w = 0; w < 4; w++) { tf += lsf[w]; tb += lsb[w]; af_ += lcf[w]; ab_ += lcb[w]; }
    atomicAdd(&sums[0], (double)tf);
    atomicAdd(&sums[1], (double)tb);
    atomicAdd(&counts[0], af_);
    atomicAdd(&counts[1], ab_);
  }
}

__global__ void k_final(const double* __restrict__ sums, const int* __restrict__ counts,
                        float* __restrict__ out) {
  if (threadIdx.x == 0 && blockIdx.x == 0) {
    double df = counts[0] > 0 ? (double)counts[0] : 1.0;
    double db = counts[1] > 0 ? (double)counts[1] : 1.0;
    out[0] = (float)(sums[0] / df + sums[1] / db);
  }
}

extern "C" void kernel_launch(void* const* d_in, const int* in_sizes, int n_in,
                              void* d_out, int out_size, void* d_ws, size_t ws_size,
                              hipStream_t stream) {
  (void)in_sizes; (void)n_in; (void)out_size; (void)ws_size;
  const float* preds = (const float*)d_in[0];  // [3,8,2,512,512] f32
  const float* cams  = (const float*)d_in[1];  // [8,1,512,512]  f32
  float* out = (float*)d_out;                  // scalar f32

  int* labels = (int*)d_ws;
  int* areas  = labels + NIMG * HWv;
  int* maxa   = areas + NIMG * HWv;
  double* sums = (double*)(maxa + 16);
  int* counts  = (int*)(sums + 2);

  const int threads = 256;

  k_local  <<<NIMG * 64, threads, 0, stream>>>(cams, labels, areas);
  k_border <<<(NIMG * 14 * Wdim + threads - 1) / threads, threads, 0, stream>>>(labels, maxa, sums, counts);
  k_flatten<<<NIMG * HWv / (threads * 4), threads, 0, stream>>>(labels, areas);
  k_max    <<<NIMG * HWv / (threads * 4), threads, 0, stream>>>(areas, maxa);
  k_keepce <<<Bsz * 64, threads, 0, stream>>>(preds, labels, areas, maxa, sums, counts);
  k_final  <<<1, 64, 0, stream>>>(sums, counts, out);
}

// Round 10
// 166.611 us; speedup vs baseline: 2.4722x; 1.2916x over previous
//
#include <hip/hip_runtime.h>
#include <hip/hip_bf16.h>
#include <math.h>

// Problem constants (reference: B=8, H=W=512)
#define Bsz    8
#define Wdim   512
#define HWv    (512 * 512)       // 262144 = 2^18
#define LOG2HW 18
#define NIMG   16                // {bg(0..7), fg(8..15)}
#define TILE   64                // 64x64 tiles -> 8x8 = 64 tiles per image
#define TPIX   (TILE * TILE)     // 4096

// ws layout (int32 units):
//   [0, NIMG*HWv)            labels: pixel -> tile root (in-tile) or -1;
//                            tile-root slots -> final root after k_flatten
//   [NIMG*HWv, 2*NIMG*HWv)   areas: tile roots hold partials; final roots
//                            hold totals after k_flatten; 0 elsewhere
//   [2*NIMG*HWv, +16)        per-image max area
//   then (8-byte aligned):   double sums[2]; int counts[2]

// ---------------- union-find (atomicMin only: parents monotone decreasing,
// links point to smaller index => lock-free correct). ----------------
__device__ __forceinline__ int uf_find(int* L, int x) {
  int p = L[x];
  while (p != x) {
    int gp = L[p];
    if (gp != p) atomicMin(&L[x], gp);  // grandparent compression (monotone)
    x = gp;
    p = L[x];
  }
  return x;
}

// Read-only find: no compression writes.
__device__ __forceinline__ int find_ro(const int* __restrict__ L, int x) {
  int p = L[x];
  while (p != x) { x = p; p = L[x]; }
  return x;
}

__device__ __forceinline__ void uf_union(int* L, int a, int b) {
  a = uf_find(L, a);
  b = uf_find(L, b);
  while (a != b) {
    if (a < b) { int t = a; a = b; b = t; }  // ensure a > b
    int old = atomicMin(&L[a], b);
    if (old == a) return;  // linked a -> b
    a = old;               // parent already lowered; keep merging
  }
}

// ---------------- kernels ----------------

// Per-tile CCL in LDS, run-based: a wave == one 64-px row. Pixels link
// directly to their run start (ballot, no atomics); vertical unions only at
// the leftmost pixel of each overlap segment. Finds are PER-RUN (run-start
// lanes only); other lanes take the root via shuffle. 1024 threads/block:
// 16 resident waves per tile to overlap the LDS chains.
__global__ __launch_bounds__(1024) void k_local(const float* __restrict__ cams,
                                                int* __restrict__ labels,
                                                int* __restrict__ areas) {
  int img  = blockIdx.x >> 6;          // 0..15
  int tile = blockIdx.x & 63;          // 8x8 tiles
  int tY = tile >> 3, tX = tile & 7;
  int b = img & 7;
  bool fg = (img & 8) != 0;
  int gbase = img << LOG2HW;
  int oy = tY * TILE, ox = tX * TILE;
  int lane = threadIdx.x & 63;

  __shared__ int P[TPIX];              // parents, 16 KB
  __shared__ int A[TPIX];              // local areas, 16 KB

  // pass 1: mask load + per-row run-start init (wave covers exactly one row)
  #pragma unroll
  for (int it = 0; it < 4; ++it) {
    int i  = it * 1024 + threadIdx.x;  // i & 63 == lane
    int ly = i >> 6;
    float c = cams[(b << LOG2HW) + ((oy + ly) << 9) + (ox + lane)];
    bool m = fg ? (c > 0.6f) : (c >= 0.2f);
    unsigned long long bm = __ballot(m);
    int par = -1;
    if (m) {
      unsigned long long below = (1ULL << lane) - 1ULL;
      unsigned long long z = (~bm) & below;       // zeros below this lane
      int rs = z ? (64 - __clzll(z)) : 0;          // run start = highest zero + 1
      par = (ly << 6) + rs;
    }
    P[i] = par;
    A[i] = 0;
  }
  __syncthreads();

  // pass 2: vertical unions, one per overlap segment (dedup via west pair)
  #pragma unroll
  for (int it = 0; it < 4; ++it) {
    int i = it * 1024 + threadIdx.x;
    if (i >= TILE && P[i] >= 0 && P[i - TILE] >= 0) {
      bool skip = (lane > 0) && (P[i - 1] >= 0) && (P[i - TILE - 1] >= 0);
      if (!skip) uf_union(P, i, i - TILE);
    }
  }
  __syncthreads();

  // pass 3: PER-RUN find + shuffle broadcast + per-run area add.
  #pragma unroll
  for (int it = 0; it < 4; ++it) {
    int i = it * 1024 + threadIdx.x;
    bool m = P[i] >= 0;
    unsigned long long bm = __ballot(m);
    int rs = 0;
    if (m) {
      unsigned long long below = (1ULL << lane) - 1ULL;
      unsigned long long z = (~bm) & below;
      rs = z ? (64 - __clzll(z)) : 0;
    }
    bool isStart = m && (rs == lane);
    int r = -1;
    if (isStart) r = find_ro(P, i);
    int root = __shfl(r, rs);          // valid wherever m
    if (m) P[i] = root;
    if (isStart) {
      unsigned long long t = (~bm) >> lane;
      int runlen = t ? (__ffsll((long long)t) - 1) : (64 - lane);
      atomicAdd(&A[root], runlen);
    }
  }
  __syncthreads();

  // pass 4: pure-read write-out: labels (global idx of tile root, fully
  // compressed) + root partial areas
  #pragma unroll
  for (int it = 0; it < 4; ++it) {
    int i  = it * 1024 + threadIdx.x;
    int ly = i >> 6;
    int g  = ((oy + ly) << 9) + (ox + lane);
    int p  = P[i];
    int lab = -1;
    if (p >= 0) lab = ((oy + (p >> 6)) << 9) + (ox + (p & 63));
    labels[gbase + g] = lab;
    areas[gbase + g]  = (p == i) ? A[i] : 0;
  }
}

// Merge across tile boundaries, one union per contiguous overlap segment.
// Also folds the tiny init (maxa/sums/counts) into block 0.
__global__ void k_border(int* __restrict__ labels, int* __restrict__ maxa,
                         double* __restrict__ sums, int* __restrict__ counts) {
  if (blockIdx.x == 0) {
    if (threadIdx.x < NIMG) maxa[threadIdx.x] = 0;
    if (threadIdx.x < 2) { sums[threadIdx.x] = 0.0; counts[threadIdx.x] = 0; }
  }
  const int per_img = 14 * Wdim;       // 7168
  int t = blockIdx.x * blockDim.x + threadIdx.x;
  if (t >= NIMG * per_img) return;
  int img = t / per_img;
  int r   = t - img * per_img;
  int k = r >> 9, j = r & (Wdim - 1);
  int* L = labels + (img << LOG2HW);
  // mask-ness (>=0 vs -1) of label slots is immutable here => dedup stable.
  if (k < 7) {                          // vertical border: x = 64k+63, union east
    int x = TILE * k + (TILE - 1);
    int p = (j << 9) + x, q = p + 1;    // j = y
    if (L[p] >= 0 && L[q] >= 0) {
      bool skip = (j > 0) && (L[p - Wdim] >= 0) && (L[q - Wdim] >= 0);
      if (!skip) uf_union(L, p, q);
    }
  } else {                              // horizontal border: y = 64(k-7)+63, union south
    int y = TILE * (k - 7) + (TILE - 1);
    int p = (y << 9) + j, q = p + Wdim; // j = x
    if (L[p] >= 0 && L[q] >= 0) {
      bool skip = (j > 0) && (L[p - 1] >= 0) && (L[q - 1] >= 0);
      if (!skip) uf_union(L, p, q);
    }
  }
}

// PUSH-ONLY flatten: only tile-root slots (area>0, ~4% of slots) do work:
// find final root, rewrite OWN label slot to it, push partial area with a
// NON-RETURNING atomic. Pixel labels untouched. Stale partials at non-final
// roots are <= component totals, so k_max is unaffected.
__global__ void k_flatten(int* __restrict__ labels, int* __restrict__ areas) {
  int t = blockIdx.x * blockDim.x + threadIdx.x;
  int idx0 = t << 2;
  int4 ar = *(const int4*)&areas[idx0];
  if ((ar.x | ar.y | ar.z | ar.w) <= 0) return;   // all >= 0
  int img  = idx0 >> LOG2HW;
  int base = img << LOG2HW;
  int* L = labels + base;
  int self0 = idx0 - base;
  int4 lab = *(const int4*)&labels[idx0];
  if (ar.x > 0) { int r = find_ro(L, lab.x); L[self0]     = r; if (r != self0)     atomicAdd(&areas[base + r], ar.x); }
  if (ar.y > 0) { int r = find_ro(L, lab.y); L[self0 + 1] = r; if (r != self0 + 1) atomicAdd(&areas[base + r], ar.y); }
  if (ar.z > 0) { int r = find_ro(L, lab.z); L[self0 + 2] = r; if (r != self0 + 2) atomicAdd(&areas[base + r], ar.z); }
  if (ar.w > 0) { int r = find_ro(L, lab.w); L[self0 + 3] = r; if (r != self0 + 3) atomicAdd(&areas[base + r], ar.w); }
}

// Per-image max area: 16 blocks/image, 16 int4 grid-stride reads per thread,
// 1 atomicMax per block (256 total, was 16384 -> killed same-line contention).
__global__ void k_max(const int* __restrict__ areas, int* __restrict__ maxa) {
  int img = blockIdx.x >> 4;           // 16 blocks per image
  int seg = blockIdx.x & 15;
  const int4* a4 = (const int4*)(areas + (img << LOG2HW));
  int base = seg * (HWv / 4 / 16);     // 4096 int4 per block
  int m = 0;
  #pragma unroll
  for (int k = 0; k < 16; ++k) {
    int4 v = a4[base + k * 256 + threadIdx.x];
    m = max(m, max(max(v.x, v.y), max(v.z, v.w)));
  }
  #pragma unroll
  for (int off = 32; off > 0; off >>= 1)
    m = max(m, __shfl_down(m, off));
  __shared__ int lm[4];
  int wave = threadIdx.x >> 6;
  if ((threadIdx.x & 63) == 0) lm[wave] = m;
  __syncthreads();
  if (threadIdx.x == 0) {
    int bm = max(max(lm[0], lm[1]), max(lm[2], lm[3]));
    if (bm > 0) atomicMax(&maxa[img], bm);
  }
}

// Fused verdict + CE, one block per (batch, tile), 1024 threads (32 waves/CU
// resident). Verdicts built once per ROOT (one gather each) into an LDS
// table; per-pixel resolution is an LDS read.
__global__ __launch_bounds__(1024) void k_keepce(const float* __restrict__ preds,
                                                 const int* __restrict__ labels,
                                                 const int* __restrict__ areas,
                                                 const int* __restrict__ maxa,
                                                 double* __restrict__ sums,
                                                 int* __restrict__ counts) {
  int b    = blockIdx.x >> 6;          // 0..7
  int tile = blockIdx.x & 63;
  int tY = tile >> 3, tX = tile & 7;
  int oy = tY * TILE, ox = tX * TILE;
  int basebg = b << LOG2HW, basefg = (8 + b) << LOG2HW;
  int maxb = maxa[b], maxf = maxa[8 + b];

  __shared__ int Vbg[TPIX];            // 16 KB verdict tables (root slots only)
  __shared__ int Vfg[TPIX];            // 16 KB

  // phase 1: stream labels+areas (one int4 group per thread); root slots
  // (area>0) resolve their verdict with ONE gather (their label already
  // holds the final root). Root pixels' register labels redirect to self.
  int i  = threadIdx.x << 2;           // in-tile index of 4-px group
  int ly = i >> 6, lx = i & 63;
  int g  = ((oy + ly) << 9) + (ox + lx);    // in-image index
  int4 lb = *(const int4*)&labels[basebg + g];
  int4 lf = *(const int4*)&labels[basefg + g];
  int4 ab = *(const int4*)&areas[basebg + g];
  int4 af = *(const int4*)&areas[basefg + g];
  if (ab.x > 0) { Vbg[i+0] = (2 * areas[basebg + lb.x] > maxb); lb.x = g + 0; }
  if (ab.y > 0) { Vbg[i+1] = (2 * areas[basebg + lb.y] > maxb); lb.y = g + 1; }
  if (ab.z > 0) { Vbg[i+2] = (2 * areas[basebg + lb.z] > maxb); lb.z = g + 2; }
  if (ab.w > 0) { Vbg[i+3] = (2 * areas[basebg + lb.w] > maxb); lb.w = g + 3; }
  if (af.x > 0) { Vfg[i+0] = (2 * areas[basefg + lf.x] > maxf); lf.x = g + 0; }
  if (af.y > 0) { Vfg[i+1] = (2 * areas[basefg + lf.y] > maxf); lf.y = g + 1; }
  if (af.z > 0) { Vfg[i+2] = (2 * areas[basefg + lf.z] > maxf); lf.z = g + 2; }
  if (af.w > 0) { Vfg[i+3] = (2 * areas[basefg + lf.w] > maxf); lf.w = g + 3; }
  __syncthreads();

  // phase 2: CE with LDS verdict lookups (in-tile: loc = (gy&63)*64+(gx&63))
  float4 A0[3], A1[3];
  #pragma unroll
  for (int p = 0; p < 3; p++) {
    const float* pb = preds + ((size_t)((p * Bsz + b) * 2) << LOG2HW);
    A0[p] = *(const float4*)&pb[g];
    A1[p] = *(const float4*)&pb[HWv + g];
  }
  int lbj[4] = {lb.x, lb.y, lb.z, lb.w};
  int lfj[4] = {lf.x, lf.y, lf.z, lf.w};
  bool vf[4], vb[4];
  #pragma unroll
  for (int j = 0; j < 4; j++) {
    int locb = (((lbj[j] >> 9) & 63) << 6) | (lbj[j] & 63);
    int locf = (((lfj[j] >> 9) & 63) << 6) | (lfj[j] & 63);
    bool kb = (lbj[j] >= 0) && (Vbg[locb] != 0);
    bool kf = (lfj[j] >= 0) && (Vfg[locf] != 0);
    vb[j] = !kb;                       // bg valid where NOT kept
    vf[j] = kf;                        // fg valid where kept
  }
  int cf = (int)vf[0] + vf[1] + vf[2] + vf[3];
  int cb = (int)vb[0] + vb[1] + vb[2] + vb[3];
  float sfg = 0.f, sbg = 0.f;
  #pragma unroll
  for (int p = 0; p < 3; p++) {
    float d[4] = {A0[p].x - A1[p].x, A0[p].y - A1[p].y,
                  A0[p].z - A1[p].z, A0[p].w - A1[p].w};
    #pragma unroll
    for (int j = 0; j < 4; j++) {
      float sp = logf(1.f + expf(-fabsf(d[j])));
      sfg += vf[j] ? (fmaxf(d[j], 0.f) + sp) : 0.f;
      sbg += vb[j] ? (fmaxf(-d[j], 0.f) + sp) : 0.f;
    }
  }
  // block reduction: wave64 shuffle -> LDS -> 4 atomics/block
  #pragma unroll
  for (int off = 32; off > 0; off >>= 1) {
    sfg += __shfl_down(sfg, off);
    sbg += __shfl_down(sbg, off);
    cf  += __shfl_down(cf, off);
    cb  += __shfl_down(cb, off);
  }
  __shared__ float lsf[16], lsb[16];
  __shared__ int   lcf[16], lcb[16];
  int wave = threadIdx.x >> 6;
  if ((threadIdx.x & 63) == 0) {
    lsf[wave] = sfg; lsb[wave] = sbg; lcf[wave] = cf; lcb[wave] = cb;
  }
  __syncthreads();
  if (threadIdx.x == 0) {
    float tf = 0.f, tb = 0.f; int af_ = 0, ab_ = 0;
    #pragma unroll
    for (int w = 0; w < 16; w++) { tf += lsf[w]; tb += lsb[w]; af_ += lcf[w]; ab_ += lcb[w]; }
    atomicAdd(&sums[0], (double)tf);
    atomicAdd(&sums[1], (double)tb);
    atomicAdd(&counts[0], af_);
    atomicAdd(&counts[1], ab_);
  }
}

__global__ void k_final(const double* __restrict__ sums, const int* __restrict__ counts,
                        float* __restrict__ out) {
  if (threadIdx.x == 0 && blockIdx.x == 0) {
    double df = counts[0] > 0 ? (double)counts[0] : 1.0;
    double db = counts[1] > 0 ? (double)counts[1] : 1.0;
    out[0] = (float)(sums[0] / df + sums[1] / db);
  }
}

extern "C" void kernel_launch(void* const* d_in, const int* in_sizes, int n_in,
                              void* d_out, int out_size, void* d_ws, size_t ws_size,
                              hipStream_t stream) {
  (void)in_sizes; (void)n_in; (void)out_size; (void)ws_size;
  const float* preds = (const float*)d_in[0];  // [3,8,2,512,512] f32
  const float* cams  = (const float*)d_in[1];  // [8,1,512,512]  f32
  float* out = (float*)d_out;                  // scalar f32

  int* labels = (int*)d_ws;
  int* areas  = labels + NIMG * HWv;
  int* maxa   = areas + NIMG * HWv;
  double* sums = (double*)(maxa + 16);
  int* counts  = (int*)(sums + 2);

  const int threads = 256;

  k_local  <<<NIMG * 64, 1024, 0, stream>>>(cams, labels, areas);
  k_border <<<(NIMG * 14 * Wdim + threads - 1) / threads, threads, 0, stream>>>(labels, maxa, sums, counts);
  k_flatten<<<NIMG * HWv / (threads * 4), threads, 0, stream>>>(labels, areas);
  k_max    <<<NIMG * 16, threads, 0, stream>>>(areas, maxa);
  k_keepce <<<Bsz * 64, 1024, 0, stream>>>(preds, labels, areas, maxa, sums, counts);
  k_final  <<<1, 64, 0, stream>>>(sums, counts, out);
}